// Round 2
// baseline (1384.496 us; speedup 1.0000x reference)
//
#include <hip/hip_runtime.h>
#include <cstdint>
#include <cstddef>

#define HW 16384
#define NEGF (-__builtin_inff())

typedef unsigned short u16;

// monotone key: float -> unsigned, order-preserving (handles negatives)
__device__ __forceinline__ unsigned fkey(float f) {
  unsigned b = __float_as_uint(f);
  return (b & 0x80000000u) ? ~b : (b | 0x80000000u);
}
__device__ __forceinline__ float funkey(unsigned u) {
  unsigned b = (u & 0x80000000u) ? (u ^ 0x80000000u) : ~u;
  return __uint_as_float(b);
}

// bf16 <-> f32 (RNE), deterministic everywhere
__device__ __forceinline__ float b2f(u16 u) {
  union { unsigned v; float f; } x; x.v = ((unsigned)u) << 16; return x.f;
}
__device__ __forceinline__ u16 f2b(float f) {
  union { float f; unsigned v; } x; x.f = f;
  unsigned r = x.v + 0x7FFFu + ((x.v >> 16) & 1u);
  return (u16)(r >> 16);
}

// ---------------- pack weights into one stacked buffer ----------------
__global__ __launch_bounds__(256) void pack_kernel(
    const float* __restrict__ Wq, const float* __restrict__ bq,
    const float* __restrict__ Wk, const float* __restrict__ bk,
    const float* __restrict__ Wv, const float* __restrict__ bv,
    float* __restrict__ Wall, float* __restrict__ ball)
{
  int i = blockIdx.x * 256 + threadIdx.x;
  if (i < 320 * 256) {
    int o = i >> 8, c = i & 255;
    float w = (o < 32) ? Wq[o * 256 + c] : (o < 64) ? Wk[(o - 32) * 256 + c]
                                                    : Wv[(o - 64) * 256 + c];
    Wall[i] = w;
  }
  if (i < 320) {
    ball[i] = (i < 32) ? bq[i] : (i < 64) ? bk[i - 32] : bv[i - 64];
  }
}

// ---------------- projections: q,k (fp32), v (bf16) = W @ x + b ----------------
// block: 64 pixels; 320 output rows chunked 10x32; thread = 4px x 2o x 10chunks
__global__ __launch_bounds__(256) void proj_kernel(
    const float* __restrict__ x1, const float* __restrict__ x2,
    const float* __restrict__ Wall, const float* __restrict__ ball,
    float* __restrict__ q, float* __restrict__ k, u16* __restrict__ v)
{
  __shared__ float xs1[32][64];
  __shared__ float xs2[32][64];
  __shared__ float ws[32][322];   // [c_chunk][o], pad->322 keeps float2 align
  __shared__ float bs[320];
  const int t = threadIdx.x;
  const int blk = blockIdx.x;
  const int b = blk >> 8;
  const int p0 = (blk & 255) << 6;

  for (int i = t; i < 320; i += 256) bs[i] = ball[i];
  __syncthreads();

  const int pg = t & 15;   // pixel group (4 px)
  const int og = t >> 4;   // o pair within 32-chunk

  float acc[10][2][4];
#pragma unroll
  for (int oc = 0; oc < 10; ++oc)
#pragma unroll
    for (int i = 0; i < 2; ++i) {
      float bv_ = bs[oc * 32 + og * 2 + i];
#pragma unroll
      for (int j = 0; j < 4; ++j) acc[oc][i][j] = bv_;
    }

  for (int c0 = 0; c0 < 256; c0 += 32) {
    __syncthreads();
#pragma unroll
    for (int r = 0; r < 8; ++r) {
      int i = t + r * 256;
      int cc = i >> 6, px = i & 63;
      size_t gb = ((size_t)(b * 256 + c0 + cc)) * HW + p0 + px;
      xs1[cc][px] = x1[gb];
      xs2[cc][px] = x2[gb];
    }
#pragma unroll
    for (int r = 0; r < 40; ++r) {
      int i = t + r * 256;
      int o = i >> 5, cc = i & 31;
      ws[cc][o] = Wall[o * 256 + c0 + cc];
    }
    __syncthreads();
#pragma unroll 4
    for (int cc = 0; cc < 32; ++cc) {
      float4 xa = *(const float4*)&xs1[cc][pg * 4];
      float4 xb = *(const float4*)&xs2[cc][pg * 4];
#pragma unroll
      for (int oc = 0; oc < 10; ++oc) {
        float2 w2 = *(const float2*)&ws[cc][oc * 32 + og * 2];
        const float4& xv = (oc == 0) ? xa : xb;
        acc[oc][0][0] = fmaf(w2.x, xv.x, acc[oc][0][0]);
        acc[oc][0][1] = fmaf(w2.x, xv.y, acc[oc][0][1]);
        acc[oc][0][2] = fmaf(w2.x, xv.z, acc[oc][0][2]);
        acc[oc][0][3] = fmaf(w2.x, xv.w, acc[oc][0][3]);
        acc[oc][1][0] = fmaf(w2.y, xv.x, acc[oc][1][0]);
        acc[oc][1][1] = fmaf(w2.y, xv.y, acc[oc][1][1]);
        acc[oc][1][2] = fmaf(w2.y, xv.z, acc[oc][1][2]);
        acc[oc][1][3] = fmaf(w2.y, xv.w, acc[oc][1][3]);
      }
    }
  }

#pragma unroll
  for (int oc = 0; oc < 10; ++oc)
#pragma unroll
    for (int i = 0; i < 2; ++i) {
      int o = og * 2 + i;
      if (oc < 2) {
        float4 val = make_float4(acc[oc][i][0], acc[oc][i][1], acc[oc][i][2], acc[oc][i][3]);
        float* dst = (oc == 0) ? q : k;
        size_t addr = ((size_t)b * 32 + o) * HW + p0 + pg * 4;
        *(float4*)&dst[addr] = val;
      } else {
        ushort4 pv;
        pv.x = f2b(acc[oc][i][0]); pv.y = f2b(acc[oc][i][1]);
        pv.z = f2b(acc[oc][i][2]); pv.w = f2b(acc[oc][i][3]);
        size_t addr = ((size_t)b * 256 + (oc - 2) * 32 + o) * HW + p0 + pg * 4;
        *(ushort4*)&v[addr] = pv;
      }
    }
}

// ---------------- spatial transpose fp32 (per 128x128 plane) ----------------
__global__ __launch_bounds__(256) void transpose_f32(
    const float* __restrict__ in, float* __restrict__ out)
{
  __shared__ float s[32][33];
  const int plane = blockIdx.y;
  const int tw = blockIdx.x & 3, th = blockIdx.x >> 2;
  const float* ip = in + (size_t)plane * HW;
  float* op = out + (size_t)plane * HW;
  const int lx = threadIdx.x & 31, ly = threadIdx.x >> 5;
  const int r0 = th << 5, c0 = tw << 5;
#pragma unroll
  for (int r = 0; r < 4; ++r) s[ly + 8 * r][lx] = ip[(r0 + ly + 8 * r) * 128 + c0 + lx];
  __syncthreads();
#pragma unroll
  for (int r = 0; r < 4; ++r) op[(c0 + ly + 8 * r) * 128 + r0 + lx] = s[lx][ly + 8 * r];
}

// ---------------- spatial transpose bf16 ----------------
__global__ __launch_bounds__(256) void transpose_b16(
    const u16* __restrict__ in, u16* __restrict__ out)
{
  __shared__ u16 s[32][33];
  const int plane = blockIdx.y;
  const int tw = blockIdx.x & 3, th = blockIdx.x >> 2;
  const u16* ip = in + (size_t)plane * HW;
  u16* op = out + (size_t)plane * HW;
  const int lx = threadIdx.x & 31, ly = threadIdx.x >> 5;
  const int r0 = th << 5, c0 = tw << 5;
#pragma unroll
  for (int r = 0; r < 4; ++r) s[ly + 8 * r][lx] = ip[(r0 + ly + 8 * r) * 128 + c0 + lx];
  __syncthreads();
#pragma unroll
  for (int r = 0; r < 4; ++r) op[(c0 + ly + 8 * r) * 128 + r0 + lx] = s[lx][ly + 8 * r];
}

// out += gamma * bf16(in)^T (per plane)
__global__ __launch_bounds__(256) void addT_kernel(
    const u16* __restrict__ in, const float* __restrict__ gptr, float* __restrict__ out)
{
  __shared__ float s[32][33];
  const int plane = blockIdx.y;
  const int tw = blockIdx.x & 3, th = blockIdx.x >> 2;
  const float g = gptr[0];
  const u16* ip = in + (size_t)plane * HW;
  float* op = out + (size_t)plane * HW;
  const int lx = threadIdx.x & 31, ly = threadIdx.x >> 5;
  const int r0 = th << 5, c0 = tw << 5;
#pragma unroll
  for (int r = 0; r < 4; ++r) s[ly + 8 * r][lx] = b2f(ip[(r0 + ly + 8 * r) * 128 + c0 + lx]);
  __syncthreads();
#pragma unroll
  for (int r = 0; r < 4; ++r) {
    size_t o = (size_t)(c0 + ly + 8 * r) * 128 + r0 + lx;
    out[0]; // no-op
    op[o] = op[o] + g * s[lx][ly + 8 * r];
  }
}

// ---------------- stats pass: exact top-64 threshold + (m, l) per row ----------------
// block = (po, b): po is w (column pass, via qT/kT) or h (row pass, via q/k)
__global__ __launch_bounds__(256) void stats_kernel(
    const float* __restrict__ qp, const float* __restrict__ kp,
    float* __restrict__ thr_out, float* __restrict__ m_out, float* __restrict__ l_out,
    int diag)
{
  __shared__ float q_s[32][128];
  __shared__ float k_s[32][132];
  __shared__ float e_s[32][132];
  const int t = threadIdx.x;
  const int po = blockIdx.x, b = blockIdx.y;

#pragma unroll
  for (int r = 0; r < 16; ++r) {
    int i = t + r * 256;
    int c = i >> 7, h = i & 127;
    size_t base = ((size_t)(b * 32 + c) * 128 + po) * 128;
    q_s[c][h] = qp[base + h];
    k_s[c][h] = kp[base + h];
  }
  __syncthreads();

  const int hh = t >> 3;
  const int gg0 = (t & 7) << 4;
  const int wv = t >> 6, ln = t & 63;

  for (int h0 = 0; h0 < 128; h0 += 32) {
    float acc[16];
#pragma unroll
    for (int j = 0; j < 16; ++j) acc[j] = 0.0f;
#pragma unroll
    for (int c = 0; c < 32; ++c) {
      float qv = q_s[c][h0 + hh];
      float4 kv[4];
      kv[0] = *(const float4*)&k_s[c][gg0];
      kv[1] = *(const float4*)&k_s[c][gg0 + 4];
      kv[2] = *(const float4*)&k_s[c][gg0 + 8];
      kv[3] = *(const float4*)&k_s[c][gg0 + 12];
#pragma unroll
      for (int j4 = 0; j4 < 4; ++j4) {
        acc[j4 * 4 + 0] = fmaf(qv, kv[j4].x, acc[j4 * 4 + 0]);
        acc[j4 * 4 + 1] = fmaf(qv, kv[j4].y, acc[j4 * 4 + 1]);
        acc[j4 * 4 + 2] = fmaf(qv, kv[j4].z, acc[j4 * 4 + 2]);
        acc[j4 * 4 + 3] = fmaf(qv, kv[j4].w, acc[j4 * 4 + 3]);
      }
    }
    if (diag) {
      int h = h0 + hh;
#pragma unroll
      for (int j = 0; j < 16; ++j)
        if (gg0 + j == h) acc[j] = NEGF;
    }
#pragma unroll
    for (int j4 = 0; j4 < 4; ++j4)
      *(float4*)&e_s[hh][gg0 + j4 * 4] =
          make_float4(acc[j4 * 4 + 0], acc[j4 * 4 + 1], acc[j4 * 4 + 2], acc[j4 * 4 + 3]);
    __syncthreads();

    for (int rr = 0; rr < 8; ++rr) {
      int row = wv * 8 + rr;
      float e0 = e_s[row][ln], e1 = e_s[row][ln + 64];
      unsigned u0 = fkey(e0), u1 = fkey(e1);
      // exact 64th-largest via bitwise binary search over order-preserving keys
      unsigned uthr = 0u;
      for (int bit = 31; bit >= 0; --bit) {
        unsigned cand = uthr | (1u << bit);
        int cnt = __popcll(__ballot(u0 >= cand)) + __popcll(__ballot(u1 >= cand));
        if (cnt >= 64) uthr = cand;
      }
      unsigned um = u0 > u1 ? u0 : u1;
#pragma unroll
      for (int off = 32; off; off >>= 1) {
        unsigned o = __shfl_xor(um, off);
        um = um > o ? um : o;
      }
      float m = funkey(um);
      float s = ((u0 >= uthr) ? __expf(e0 - m) : 0.0f) +
                ((u1 >= uthr) ? __expf(e1 - m) : 0.0f);
#pragma unroll
      for (int off = 32; off; off >>= 1) s += __shfl_xor(s, off);
      if (ln == 0) {
        size_t idx = ((size_t)b * 128 + po) * 128 + h0 + row;
        thr_out[idx] = __uint_as_float(uthr);
        m_out[idx] = m;
        l_out[idx] = s;
      }
    }
    __syncthreads();
  }
}

// ---------------- output pass: out[c][i] = sum_j v[c][j] * att[i][j] ----------------
// block = (i-tile of 32, po, b); thread t = channel c; recomputes e bit-identically
// FUSE=1: writes fp32 out with gamma*acc + x1.  FUSE=0: writes bf16 accH.
template <int DIAG, int FUSE>
__global__ __launch_bounds__(256) void out_kernel(
    const float* __restrict__ qp, const float* __restrict__ kp, const u16* __restrict__ vp,
    const float* __restrict__ thr_own, const float* __restrict__ m_own, const float* __restrict__ l_own,
    const float* __restrict__ m_oth, const float* __restrict__ l_oth,
    const float* __restrict__ x1, const float* __restrict__ gptr,
    void* __restrict__ outp_v)
{
  __shared__ float q_s[32][36];
  __shared__ float k_s[32][132];
  __shared__ float att_s[32][36];   // [j][i]
  __shared__ float m_s[32], il_s[32];
  __shared__ unsigned ut_s[32];
  const int t = threadIdx.x;
  const int i0 = blockIdx.x << 5;
  const int po = blockIdx.y, b = blockIdx.z;

  {
    int c = t >> 3, ii4 = (t & 7) << 2;
    size_t base = ((size_t)(b * 32 + c) * 128 + po) * 128 + i0 + ii4;
    *(float4*)&q_s[c][ii4] = *(const float4*)&qp[base];
  }
#pragma unroll
  for (int r = 0; r < 4; ++r) {
    int i = t + r * 256;
    int c = i >> 5, g4 = (i & 31) << 2;
    *(float4*)&k_s[c][g4] = *(const float4*)&kp[((size_t)(b * 32 + c) * 128 + po) * 128 + g4];
  }
  if (t < 32) {
    size_t own = ((size_t)b * 128 + po) * 128 + i0 + t;
    size_t oth = ((size_t)b * 128 + i0 + t) * 128 + po;
    float ma = m_own[own], la = l_own[own];
    float mb = m_oth[oth], lb = l_oth[oth];
    float m = fmaxf(ma, mb);
    float l = la * __expf(ma - m) + lb * __expf(mb - m);
    m_s[t] = m;
    il_s[t] = 1.0f / l;
    ut_s[t] = __float_as_uint(thr_own[own]);
  }

  float acc[32];
#pragma unroll
  for (int i = 0; i < 32; ++i) acc[i] = 0.0f;

  const int ii = t & 31;
  const int j0 = (t >> 5) << 2;

  for (int gc = 0; gc < 4; ++gc) {
    float vr[32];
    {
      size_t base = ((size_t)(b * 256 + t) * 128 + po) * 128 + gc * 32;
#pragma unroll
      for (int j4 = 0; j4 < 8; ++j4) {
        ushort4 tmp = *(const ushort4*)&vp[base + j4 * 4];
        vr[j4 * 4 + 0] = b2f(tmp.x); vr[j4 * 4 + 1] = b2f(tmp.y);
        vr[j4 * 4 + 2] = b2f(tmp.z); vr[j4 * 4 + 3] = b2f(tmp.w);
      }
    }
    __syncthreads();   // gc=0: fills+stats ready; gc>0: att_s consumers done
    {
      float e[4] = {0.0f, 0.0f, 0.0f, 0.0f};
#pragma unroll
      for (int c = 0; c < 32; ++c) {
        float qv = q_s[c][ii];
        float4 kv = *(const float4*)&k_s[c][gc * 32 + j0];
        e[0] = fmaf(qv, kv.x, e[0]);
        e[1] = fmaf(qv, kv.y, e[1]);
        e[2] = fmaf(qv, kv.z, e[2]);
        e[3] = fmaf(qv, kv.w, e[3]);
      }
#pragma unroll
      for (int jj = 0; jj < 4; ++jj) {
        float a;
        int jg = gc * 32 + j0 + jj;
        if (DIAG && jg == i0 + ii) {
          a = 0.0f;
        } else {
          unsigned ue = fkey(e[jj]);
          a = (ue >= ut_s[ii]) ? __expf(e[jj] - m_s[ii]) * il_s[ii] : 0.0f;
        }
        att_s[j0 + jj][ii] = a;
      }
    }
    __syncthreads();
#pragma unroll
    for (int j = 0; j < 32; ++j) {
      float vv = vr[j];
#pragma unroll
      for (int i4 = 0; i4 < 8; ++i4) {
        float4 a = *(const float4*)&att_s[j][i4 * 4];
        acc[i4 * 4 + 0] = fmaf(vv, a.x, acc[i4 * 4 + 0]);
        acc[i4 * 4 + 1] = fmaf(vv, a.y, acc[i4 * 4 + 1]);
        acc[i4 * 4 + 2] = fmaf(vv, a.z, acc[i4 * 4 + 2]);
        acc[i4 * 4 + 3] = fmaf(vv, a.w, acc[i4 * 4 + 3]);
      }
    }
  }

  size_t obase = ((size_t)(b * 256 + t) * 128 + po) * 128 + i0;
  if (FUSE) {
    const float g = gptr[0];
    float* outp = (float*)outp_v;
#pragma unroll
    for (int i4 = 0; i4 < 8; ++i4) {
      float4 xv = *(const float4*)&x1[obase + i4 * 4];
      float4 o;
      o.x = g * acc[i4 * 4 + 0] + xv.x;
      o.y = g * acc[i4 * 4 + 1] + xv.y;
      o.z = g * acc[i4 * 4 + 2] + xv.z;
      o.w = g * acc[i4 * 4 + 3] + xv.w;
      *(float4*)&outp[obase + i4 * 4] = o;
    }
  } else {
    u16* outp = (u16*)outp_v;
#pragma unroll
    for (int i4 = 0; i4 < 8; ++i4) {
      ushort4 o;
      o.x = f2b(acc[i4 * 4 + 0]); o.y = f2b(acc[i4 * 4 + 1]);
      o.z = f2b(acc[i4 * 4 + 2]); o.w = f2b(acc[i4 * 4 + 3]);
      *(ushort4*)&outp[obase + i4 * 4] = o;
    }
  }
}

// ---------------- launch ----------------
// ws budget (bytes): header 329,216+1,792 | q,k,qT,kT fp32 67,108,864
// | stats 3,145,728 | v bf16 67,108,864 | vT bf16 67,108,864  => 204,801,536 total.
// accH (bf16) aliases v: the W-pass out_kernel is the last reader of v and runs
// before the H-pass out_kernel writes accH.
extern "C" void kernel_launch(void* const* d_in, const int* in_sizes, int n_in,
                              void* d_out, int out_size, void* d_ws, size_t ws_size,
                              hipStream_t stream)
{
  const float* x1 = (const float*)d_in[0];
  const float* x2 = (const float*)d_in[1];
  const float* Wq = (const float*)d_in[2];
  const float* bq = (const float*)d_in[3];
  const float* Wk = (const float*)d_in[4];
  const float* bk = (const float*)d_in[5];
  const float* Wv = (const float*)d_in[6];
  const float* bv = (const float*)d_in[7];
  const float* gm = (const float*)d_in[8];
  float* out = (float*)d_out;
  float* ws = (float*)d_ws;

  float* Wall  = ws;                      // 81920 f
  float* ball  = ws + 81920;              // 384 f (pad to 82304)
  float* q     = ws + 82304;              // 4,194,304 f
  float* k     = q + 4194304;
  float* qT    = k + 4194304;
  float* kT    = qT + 4194304;
  float* stats = kT + 4194304;            // 786,432 f
  u16*   v     = (u16*)(stats + 786432);  // 33,554,432 bf16
  u16*   vT    = v + 33554432;            // 33,554,432 bf16
  u16*   accH  = v;                       // alias (v dead after W out pass)

  float* thrH = stats;
  float* mH   = stats + 131072;
  float* lH   = stats + 262144;
  float* thrW = stats + 393216;
  float* mW   = stats + 524288;
  float* lW   = stats + 655360;

  pack_kernel<<<320, 256, 0, stream>>>(Wq, bq, Wk, bk, Wv, bv, Wall, ball);
  proj_kernel<<<2048, 256, 0, stream>>>(x1, x2, Wall, ball, q, k, v);
  transpose_f32<<<dim3(16, 256), 256, 0, stream>>>(q, qT);
  transpose_f32<<<dim3(16, 256), 256, 0, stream>>>(k, kT);
  transpose_b16<<<dim3(16, 2048), 256, 0, stream>>>(v, vT);
  stats_kernel<<<dim3(128, 8), 256, 0, stream>>>(qT, kT, thrH, mH, lH, 1);
  stats_kernel<<<dim3(128, 8), 256, 0, stream>>>(q, k, thrW, mW, lW, 0);
  // W pass first (last reader of v), fused with gamma & +x1 into out:
  out_kernel<0, 1><<<dim3(4, 128, 8), 256, 0, stream>>>(
      q, k, v, thrW, mW, lW, mH, lH, x1, gm, (void*)out);
  // H pass writes transposed accumulator into the (now dead) v region:
  out_kernel<1, 0><<<dim3(4, 128, 8), 256, 0, stream>>>(
      qT, kT, vT, thrH, mH, lH, mW, lW, x1, gm, (void*)accH);
  addT_kernel<<<dim3(16, 2048), 256, 0, stream>>>(accH, gm, out);
}